// Round 1
// baseline (3640.784 us; speedup 1.0000x reference)
//
#include <hip/hip_runtime.h>
#include <stdint.h>

#define Bsz 256
#define Tt  128
#define INs 256
#define Hh  512

typedef __attribute__((ext_vector_type(8))) short short8;
typedef __attribute__((ext_vector_type(4))) float f32x4;

__device__ __forceinline__ unsigned short f2bf(float f) {
  union { float f; unsigned int u; } v; v.f = f;
  unsigned int u = v.u;
  u += 0x7FFFu + ((u >> 16) & 1u);   // round-to-nearest-even
  return (unsigned short)(u >> 16);
}
__device__ __forceinline__ float bf2f(unsigned short h) {
  union { unsigned int u; float f; } v; v.u = ((unsigned int)h) << 16;
  return v.f;
}
__device__ __forceinline__ float sigf(float x) { return 1.0f / (1.0f + expf(-x)); }

// ---- ws layout (bytes) ----
#define WS_CTR  0
#define WS_H0   4096
#define WS_H1   (WS_H0 + 2 * Bsz * Hh * 2)
#define WS_C0   (WS_H1 + 2 * Bsz * Hh * 2)
#define WS_C1   (WS_C0 + Bsz * Hh * 4)
#define WS_ZERO_BYTES (WS_C1 + Bsz * Hh * 4)   // 2101248

#define GL_STRIDE 65
#define W_BYTES   131072
#define DYN_SHMEM (W_BYTES + 64 * GL_STRIDE * 4)   // 147712

#define MFMA4(A0, A1, B0, B1)                                                   \
  acc00 = __builtin_amdgcn_mfma_f32_16x16x32_bf16(A0, B0, acc00, 0, 0, 0);      \
  acc01 = __builtin_amdgcn_mfma_f32_16x16x32_bf16(A0, B1, acc01, 0, 0, 0);      \
  acc10 = __builtin_amdgcn_mfma_f32_16x16x32_bf16(A1, B0, acc10, 0, 0, 0);      \
  acc11 = __builtin_amdgcn_mfma_f32_16x16x32_bf16(A1, B1, acc11, 0, 0, 0);

extern "C" __global__ void __launch_bounds__(256)
lstm_fused(const float* __restrict__ x,
           const float* __restrict__ Wx0, const float* __restrict__ bx0,
           const float* __restrict__ Wh0, const float* __restrict__ Wc0,
           const float* __restrict__ Wx1, const float* __restrict__ bx1,
           const float* __restrict__ Wh1, const float* __restrict__ Wc1,
           const float* __restrict__ Wfc, const float* __restrict__ bfc,
           float* __restrict__ out, unsigned char* __restrict__ ws)
{
  extern __shared__ char smem[];
  unsigned int*   ctr = (unsigned int*)(ws + WS_CTR);
  unsigned short* h0b = (unsigned short*)(ws + WS_H0);
  unsigned short* h1b = (unsigned short*)(ws + WS_H1);
  float* c0s = (float*)(ws + WS_C0);
  float* c1s = (float*)(ws + WS_C1);
  float* gl  = (float*)(smem + W_BYTES);

  const int wg    = blockIdx.x;
  const int rb    = wg >> 6;        // batch-row group (0..3), 64 rows each
  const int sub   = wg & 63;
  const int layer = sub >> 5;       // 0: layer0 tiles, 1: layer1 tiles
  const int cb    = sub & 31;       // hidden col block (16 units)
  const int tid   = threadIdx.x;
  const int lane  = tid & 63;
  const int wave  = tid >> 6;
  const int wm    = wave >> 1, wn = wave & 1;
  const int j0    = cb << 4;

  // ---- preload this WG's weight slice into LDS, bf16, fragment order ----
  {
    const int K   = layer ? 1024 : 768;
    const int k8s = K >> 3;
    const int ng  = 64 * k8s;
    for (int idx = tid; idx < ng; idx += 256) {
      const int nl = idx / k8s;           // local gate-col 0..63
      const int k8 = idx - nl * k8s;
      const int k  = k8 << 3;
      const int nrow = (nl >> 4) * Hh + j0 + (nl & 15);  // gate*512 + j
      const float* src;
      if (!layer) src = (k < INs) ? (Wx0 + (size_t)nrow * INs + k)
                                  : (Wh0 + (size_t)nrow * Hh + (k - INs));
      else        src = (k < Hh)  ? (Wx1 + (size_t)nrow * Hh + k)
                                  : (Wh1 + (size_t)nrow * Hh + (k - Hh));
      short8 v;
      #pragma unroll
      for (int j = 0; j < 8; ++j) v[j] = (short)f2bf(src[j]);
      const int slot = ((k8 >> 2) * 4 + (nl >> 4)) * 64 + ((k8 & 3) * 16 + (nl & 15));
      *(short8*)(smem + slot * 16) = v;
    }
  }
  __syncthreads();

  const int mrow = (wm << 5) + (lane & 15);
  const int koff = (lane >> 4) << 3;
  const int bg0  = (rb << 6) + mrow;      // global batch row (mf=0); mf=1 -> +16

  for (int p = 0; p <= Tt; ++p) {
    const bool work = layer ? (p >= 1) : (p < Tt);
    if (work) {
      f32x4 zz = {0.f, 0.f, 0.f, 0.f};
      f32x4 acc00 = zz, acc01 = zz, acc10 = zz, acc11 = zz;
      const int bufR = (p - 1) & 1;

      if (!layer) {
        const int t = p;
        // x-part: ksteps 0..7 (fp32 -> bf16 on the fly)
        const float* xp0 = x + ((size_t)bg0 * Tt + t) * INs + koff;
        const float* xp1 = xp0 + (size_t)16 * Tt * INs;
        #pragma unroll 2
        for (int ks = 0; ks < 8; ++ks) {
          const float* s0 = xp0 + ks * 32;
          const float* s1 = xp1 + ks * 32;
          short8 a0, a1;
          #pragma unroll
          for (int j = 0; j < 8; ++j) { a0[j] = (short)f2bf(s0[j]); a1[j] = (short)f2bf(s1[j]); }
          const char* bb = smem + (((ks << 2) + (wn << 1)) * 64 + lane) * 16;
          short8 b0v = *(const short8*)bb;
          short8 b1v = *(const short8*)(bb + 1024);
          MFMA4(a0, a1, b0v, b1v)
        }
        // h-part: ksteps 8..23, A = h0[t-1] (bf16, direct global)
        const unsigned short* hp0 = h0b + (size_t)bufR * (Bsz * Hh) + (size_t)bg0 * Hh + koff;
        const unsigned short* hp1 = hp0 + 16 * Hh;
        #pragma unroll 4
        for (int ks = 0; ks < 16; ++ks) {
          short8 a0 = *(const short8*)(hp0 + ks * 32);
          short8 a1 = *(const short8*)(hp1 + ks * 32);
          const char* bb = smem + ((((ks + 8) << 2) + (wn << 1)) * 64 + lane) * 16;
          short8 b0v = *(const short8*)bb;
          short8 b1v = *(const short8*)(bb + 1024);
          MFMA4(a0, a1, b0v, b1v)
        }
      } else {
        // layer1, step t = p-1:  gates = h0[t] @ Wx1^T + h1[t-1] @ Wh1^T
        const unsigned short* ap0 = h0b + (size_t)bufR * (Bsz * Hh) + (size_t)bg0 * Hh + koff;
        const unsigned short* ap1 = ap0 + 16 * Hh;
        #pragma unroll 4
        for (int ks = 0; ks < 16; ++ks) {
          short8 a0 = *(const short8*)(ap0 + ks * 32);
          short8 a1 = *(const short8*)(ap1 + ks * 32);
          const char* bb = smem + (((ks << 2) + (wn << 1)) * 64 + lane) * 16;
          short8 b0v = *(const short8*)bb;
          short8 b1v = *(const short8*)(bb + 1024);
          MFMA4(a0, a1, b0v, b1v)
        }
        const unsigned short* bp0 = h1b + (size_t)(p & 1) * (Bsz * Hh) + (size_t)bg0 * Hh + koff;
        const unsigned short* bp1 = bp0 + 16 * Hh;
        #pragma unroll 4
        for (int ks = 0; ks < 16; ++ks) {
          short8 a0 = *(const short8*)(bp0 + ks * 32);
          short8 a1 = *(const short8*)(bp1 + ks * 32);
          const char* bb = smem + ((((ks + 16) << 2) + (wn << 1)) * 64 + lane) * 16;
          short8 b0v = *(const short8*)bb;
          short8 b1v = *(const short8*)(bb + 1024);
          MFMA4(a0, a1, b0v, b1v)
        }
      }

      // ---- stash gate tile to LDS (C-frag: row=(l>>4)*4+v, col=l&15) ----
      {
        const int r0 = (wm << 5) + ((lane >> 4) << 2);
        const int cA = (wn << 5) + (lane & 15);
        #pragma unroll
        for (int v = 0; v < 4; ++v) {
          gl[(r0 + v) * GL_STRIDE + cA]           = acc00[v];
          gl[(r0 + v) * GL_STRIDE + cA + 16]      = acc01[v];
          gl[(r0 + 16 + v) * GL_STRIDE + cA]      = acc10[v];
          gl[(r0 + 16 + v) * GL_STRIDE + cA + 16] = acc11[v];
        }
      }
      __syncthreads();

      // ---- fused peephole elementwise: 1024 cells, 4/thread ----
      const float* bx = layer ? bx1 : bx0;
      const float* Wc = layer ? Wc1 : Wc0;
      float* cst = layer ? c1s : c0s;
      unsigned short* hdst = layer ? (h1b + (size_t)((p - 1) & 1) * (Bsz * Hh))
                                   : (h0b + (size_t)(p & 1) * (Bsz * Hh));
      #pragma unroll
      for (int q = 0; q < 4; ++q) {
        const int cell = (q << 8) + tid;
        const int bl = cell >> 4, jj = cell & 15;
        const int jg = j0 + jj;
        const size_t sidx = (size_t)((rb << 6) + bl) * Hh + jg;
        const float* glr = gl + bl * GL_STRIDE + jj;
        float gi = glr[0]  + bx[jg];
        float gf = glr[16] + bx[Hh + jg];
        float gg = glr[32] + bx[2 * Hh + jg];
        float go = glr[48] + bx[3 * Hh + jg];
        float cold = cst[sidx];
        float iv = sigf(gi + cold * Wc[jg]);
        float fv = sigf(gf + cold * Wc[Hh + jg]);
        float gv = tanhf(gg);
        float cn = fv * cold + iv * gv;
        float ov = sigf(go + cn * Wc[2 * Hh + jg]);
        cst[sidx] = cn;
        hdst[sidx] = f2bf(ov * tanhf(cn));
      }
    }

    // ---- per-group barrier (64 WGs), monotonic counter ----
    __syncthreads();
    if (tid == 0) {
      __hip_atomic_fetch_add(&ctr[rb << 6], 1u, __ATOMIC_RELEASE, __HIP_MEMORY_SCOPE_AGENT);
      const unsigned int tgt = (unsigned int)(p + 1) * 64u;
      while (__hip_atomic_load(&ctr[rb << 6], __ATOMIC_ACQUIRE, __HIP_MEMORY_SCOPE_AGENT) < tgt)
        __builtin_amdgcn_s_sleep(1);
    }
    __syncthreads();
  }

  // ---- final FC: out[wg][0..7] = h1_final[wg] @ Wfc^T + bfc ----
  const unsigned short* hf = h1b + (size_t)(Bsz * Hh);  // buffer 1 holds h1[127]
  float* red = (float*)smem;                            // W region dead now
  const int cc = tid & 7, ksl = tid >> 3;
  const unsigned short* hr = hf + (size_t)wg * Hh + ksl * 16;
  const float* wr = Wfc + (size_t)cc * Hh + ksl * 16;
  float s = 0.f;
  #pragma unroll
  for (int k = 0; k < 16; ++k) s += bf2f(hr[k]) * wr[k];
  red[tid] = s;
  __syncthreads();
  if (tid < 8) {
    float a = bfc[tid];
    #pragma unroll
    for (int i = 0; i < 32; ++i) a += red[i * 8 + tid];
    out[wg * 8 + tid] = a;
  }
}

extern "C" void kernel_launch(void* const* d_in, const int* in_sizes, int n_in,
                              void* d_out, int out_size, void* d_ws, size_t ws_size,
                              hipStream_t stream) {
  if (ws_size < (size_t)WS_ZERO_BYTES) return;  // loud fail instead of corruption

  const float* x   = (const float*)d_in[0];
  const float* Wx0 = (const float*)d_in[1];
  const float* bx0 = (const float*)d_in[2];
  const float* Wh0 = (const float*)d_in[3];
  const float* Wc0 = (const float*)d_in[4];
  const float* Wx1 = (const float*)d_in[5];
  const float* bx1 = (const float*)d_in[6];
  const float* Wh1 = (const float*)d_in[7];
  const float* Wc1 = (const float*)d_in[8];
  const float* Wfc = (const float*)d_in[9];
  const float* bfc = (const float*)d_in[10];
  float* out = (float*)d_out;
  unsigned char* ws = (unsigned char*)d_ws;

  hipMemsetAsync(d_ws, 0, WS_ZERO_BYTES, stream);
  hipFuncSetAttribute(reinterpret_cast<const void*>(lstm_fused),
                      hipFuncAttributeMaxDynamicSharedMemorySize, DYN_SHMEM);
  void* args[] = {&x, &Wx0, &bx0, &Wh0, &Wc0, &Wx1, &bx1, &Wh1, &Wc1, &Wfc, &bfc, &out, &ws};
  hipLaunchCooperativeKernel((void*)lstm_fused, dim3(256), dim3(256), args,
                             (unsigned int)DYN_SHMEM, stream);
}

// Round 3
// 2213.273 us; speedup vs baseline: 1.6450x; 1.6450x over previous
//
#include <hip/hip_runtime.h>
#include <stdint.h>

#define Bsz 256
#define Tt  128
#define INs 256
#define Hh  512

typedef __attribute__((ext_vector_type(8))) short short8;
typedef __attribute__((ext_vector_type(4))) float f32x4;

__device__ __forceinline__ unsigned short f2bf(float f) {
  union { float f; unsigned int u; } v; v.f = f;
  unsigned int u = v.u;
  u += 0x7FFFu + ((u >> 16) & 1u);   // round-to-nearest-even
  return (unsigned short)(u >> 16);
}
__device__ __forceinline__ float bf2f(unsigned short h) {
  union { unsigned int u; float f; } v; v.u = ((unsigned int)h) << 16;
  return v.f;
}
__device__ __forceinline__ float sigf(float x) { return 1.0f / (1.0f + expf(-x)); }

// ---- ws layout (bytes) ----
// flags: 256 WGs x 64B stride (u32 used)
#define WS_FLAGS 0
#define WS_H0    16384
#define WS_H1    (WS_H0 + 2 * Bsz * Hh * 2)
#define WS_ZERO_BYTES (WS_H1 + 2 * Bsz * Hh * 2)   // 16K + 1M = 1065088

#define GL_STRIDE 65
#define W_BYTES   131072
#define GL_BYTES  (64 * GL_STRIDE * 4)             // 16640
#define BW_OFF    (W_BYTES + GL_BYTES)
#define DYN_SHMEM (BW_OFF + 64 * 4 + 48 * 4)       // 148160

#define MFMA4(A0, A1, B0, B1)                                                   \
  acc00 = __builtin_amdgcn_mfma_f32_16x16x32_bf16(A0, B0, acc00, 0, 0, 0);      \
  acc01 = __builtin_amdgcn_mfma_f32_16x16x32_bf16(A0, B1, acc01, 0, 0, 0);      \
  acc10 = __builtin_amdgcn_mfma_f32_16x16x32_bf16(A1, B0, acc10, 0, 0, 0);      \
  acc11 = __builtin_amdgcn_mfma_f32_16x16x32_bf16(A1, B1, acc11, 0, 0, 0);

extern "C" __global__ void __launch_bounds__(256)
lstm_fused(const float* __restrict__ x,
           const float* __restrict__ Wx0, const float* __restrict__ bx0,
           const float* __restrict__ Wh0, const float* __restrict__ Wc0,
           const float* __restrict__ Wx1, const float* __restrict__ bx1,
           const float* __restrict__ Wh1, const float* __restrict__ Wc1,
           const float* __restrict__ Wfc, const float* __restrict__ bfc,
           float* __restrict__ out, unsigned char* __restrict__ ws)
{
  extern __shared__ char smem[];
  unsigned int*   flg = (unsigned int*)(ws + WS_FLAGS);
  unsigned short* h0b = (unsigned short*)(ws + WS_H0);
  unsigned short* h1b = (unsigned short*)(ws + WS_H1);
  float* gl  = (float*)(smem + W_BYTES);
  float* bxl = (float*)(smem + BW_OFF);        // 64 floats: bias per local gate-col
  float* wcl = bxl + 64;                       // 48 floats: peephole weights

  const int wg    = blockIdx.x;
  const int rb    = wg >> 6;        // batch-row group (0..3), 64 rows each
  const int sub   = wg & 63;
  const int layer = sub >> 5;       // 0: layer0 tiles, 1: layer1 tiles
  const int cb    = sub & 31;       // hidden col block (16 units)
  const int tid   = threadIdx.x;
  const int lane  = tid & 63;
  const int wave  = tid >> 6;
  const int wm    = wave >> 1, wn = wave & 1;
  const int j0    = cb << 4;

  // ---- preload this WG's weight slice into LDS, bf16, fragment order ----
  {
    const int K   = layer ? 1024 : 768;
    const int k8s = K >> 3;
    const int ng  = 64 * k8s;
    for (int idx = tid; idx < ng; idx += 256) {
      const int nl = idx / k8s;           // local gate-col 0..63
      const int k8 = idx - nl * k8s;
      const int k  = k8 << 3;
      const int nrow = (nl >> 4) * Hh + j0 + (nl & 15);  // gate*512 + j
      const float* src;
      if (!layer) src = (k < INs) ? (Wx0 + (size_t)nrow * INs + k)
                                  : (Wh0 + (size_t)nrow * Hh + (k - INs));
      else        src = (k < Hh)  ? (Wx1 + (size_t)nrow * Hh + k)
                                  : (Wh1 + (size_t)nrow * Hh + (k - Hh));
      short8 v;
      #pragma unroll
      for (int j = 0; j < 8; ++j) v[j] = (short)f2bf(src[j]);
      const int slot = ((k8 >> 2) * 4 + (nl >> 4)) * 64 + ((k8 & 3) * 16 + (nl & 15));
      *(short8*)(smem + slot * 16) = v;
    }
  }
  // ---- preload bias + peephole weights for this WG's 16 hidden cols ----
  {
    const float* bx = layer ? bx1 : bx0;
    const float* Wc = layer ? Wc1 : Wc0;
    if (tid < 64) bxl[tid] = bx[(tid >> 4) * Hh + j0 + (tid & 15)];
    if (tid < 48) wcl[tid] = Wc[(tid >> 4) * Hh + j0 + (tid & 15)];
  }
  __syncthreads();

  const int mrow = (wm << 5) + (lane & 15);
  const int koff = (lane >> 4) << 3;
  const int bg0  = (rb << 6) + mrow;      // global batch row (mf=0); mf=1 -> +16

  // ---- WG-private cell state in registers: thread owns row (tid>>2), cols qq*4.. ----
  const int er = tid >> 2;          // local row 0..63
  const int eq = tid & 3;           // col quad 0..3
  float cr0 = 0.f, cr1 = 0.f, cr2 = 0.f, cr3 = 0.f;

  for (int p = 0; p <= Tt; ++p) {
    const bool work = layer ? (p >= 1) : (p < Tt);
    if (work) {
      f32x4 zz = {0.f, 0.f, 0.f, 0.f};
      f32x4 acc00 = zz, acc01 = zz, acc10 = zz, acc11 = zz;
      const int bufR = (p - 1) & 1;

      if (!layer) {
        const int t = p;
        // x-part: ksteps 0..7 (fp32 -> bf16 on the fly)
        const float* xp0 = x + ((size_t)bg0 * Tt + t) * INs + koff;
        const float* xp1 = xp0 + (size_t)16 * Tt * INs;
        #pragma unroll 2
        for (int ks = 0; ks < 8; ++ks) {
          const float* s0 = xp0 + ks * 32;
          const float* s1 = xp1 + ks * 32;
          short8 a0, a1;
          #pragma unroll
          for (int j = 0; j < 8; ++j) { a0[j] = (short)f2bf(s0[j]); a1[j] = (short)f2bf(s1[j]); }
          const char* bb = smem + (((ks << 2) + (wn << 1)) * 64 + lane) * 16;
          short8 b0v = *(const short8*)bb;
          short8 b1v = *(const short8*)(bb + 1024);
          MFMA4(a0, a1, b0v, b1v)
        }
        // h-part: ksteps 8..23, A = h0[t-1] (bf16, direct global)
        const unsigned short* hp0 = h0b + (size_t)bufR * (Bsz * Hh) + (size_t)bg0 * Hh + koff;
        const unsigned short* hp1 = hp0 + 16 * Hh;
        #pragma unroll 4
        for (int ks = 0; ks < 16; ++ks) {
          short8 a0 = *(const short8*)(hp0 + ks * 32);
          short8 a1 = *(const short8*)(hp1 + ks * 32);
          const char* bb = smem + ((((ks + 8) << 2) + (wn << 1)) * 64 + lane) * 16;
          short8 b0v = *(const short8*)bb;
          short8 b1v = *(const short8*)(bb + 1024);
          MFMA4(a0, a1, b0v, b1v)
        }
      } else {
        // layer1, step t = p-1:  gates = h0[t] @ Wx1^T + h1[t-1] @ Wh1^T
        const unsigned short* ap0 = h0b + (size_t)bufR * (Bsz * Hh) + (size_t)bg0 * Hh + koff;
        const unsigned short* ap1 = ap0 + 16 * Hh;
        #pragma unroll 4
        for (int ks = 0; ks < 16; ++ks) {
          short8 a0 = *(const short8*)(ap0 + ks * 32);
          short8 a1 = *(const short8*)(ap1 + ks * 32);
          const char* bb = smem + (((ks << 2) + (wn << 1)) * 64 + lane) * 16;
          short8 b0v = *(const short8*)bb;
          short8 b1v = *(const short8*)(bb + 1024);
          MFMA4(a0, a1, b0v, b1v)
        }
        const unsigned short* bp0 = h1b + (size_t)(p & 1) * (Bsz * Hh) + (size_t)bg0 * Hh + koff;
        const unsigned short* bp1 = bp0 + 16 * Hh;
        #pragma unroll 4
        for (int ks = 0; ks < 16; ++ks) {
          short8 a0 = *(const short8*)(bp0 + ks * 32);
          short8 a1 = *(const short8*)(bp1 + ks * 32);
          const char* bb = smem + ((((ks + 16) << 2) + (wn << 1)) * 64 + lane) * 16;
          short8 b0v = *(const short8*)bb;
          short8 b1v = *(const short8*)(bb + 1024);
          MFMA4(a0, a1, b0v, b1v)
        }
      }

      // ---- stash gate tile to LDS (C-frag: row=(l>>4)*4+v, col=l&15) ----
      {
        const int r0 = (wm << 5) + ((lane >> 4) << 2);
        const int cA = (wn << 5) + (lane & 15);
        #pragma unroll
        for (int v = 0; v < 4; ++v) {
          gl[(r0 + v) * GL_STRIDE + cA]           = acc00[v];
          gl[(r0 + v) * GL_STRIDE + cA + 16]      = acc01[v];
          gl[(r0 + 16 + v) * GL_STRIDE + cA]      = acc10[v];
          gl[(r0 + 16 + v) * GL_STRIDE + cA + 16] = acc11[v];
        }
      }
      __syncthreads();

      // ---- fused peephole elementwise: thread -> row er, cols eq*4..eq*4+3 ----
      {
        unsigned short* hdst = layer ? (h1b + (size_t)((p - 1) & 1) * (Bsz * Hh))
                                     : (h0b + (size_t)(p & 1) * (Bsz * Hh));
        const float* glr = gl + er * GL_STRIDE;
        unsigned long long hv = 0;
        float cprev[4] = {cr0, cr1, cr2, cr3};
        float cnew[4];
        #pragma unroll
        for (int k = 0; k < 4; ++k) {
          const int jj = (eq << 2) + k;
          float gi = glr[jj]      + bxl[jj];
          float gf = glr[16 + jj] + bxl[16 + jj];
          float gg = glr[32 + jj] + bxl[32 + jj];
          float go = glr[48 + jj] + bxl[48 + jj];
          float co = cprev[k];
          float iv = sigf(gi + co * wcl[jj]);
          float fv = sigf(gf + co * wcl[16 + jj]);
          float gv = tanhf(gg);
          float cn = fv * co + iv * gv;
          float ov = sigf(go + cn * wcl[32 + jj]);
          cnew[k] = cn;
          unsigned long long hb = (unsigned long long)f2bf(ov * tanhf(cn));
          hv |= hb << (16 * k);
        }
        cr0 = cnew[0]; cr1 = cnew[1]; cr2 = cnew[2]; cr3 = cnew[3];
        const size_t sidx = (size_t)((rb << 6) + er) * Hh + j0 + (eq << 2);
        __hip_atomic_store((unsigned long long*)(hdst + sidx), hv,
                           __ATOMIC_RELAXED, __HIP_MEMORY_SCOPE_AGENT);
      }
    }

    // ---- distributed flag barrier over this group's 64 WGs ----
    __syncthreads();
    if (wave == 0) {
      const unsigned int tgt = (unsigned int)(p + 1);
      if (lane == 0)
        __hip_atomic_store(&flg[wg << 4], tgt, __ATOMIC_RELEASE, __HIP_MEMORY_SCOPE_AGENT);
      unsigned int* myf = &flg[((rb << 6) + lane) << 4];
      for (;;) {
        unsigned int v = __hip_atomic_load(myf, __ATOMIC_RELAXED, __HIP_MEMORY_SCOPE_AGENT);
        if (__ballot(v >= tgt) == ~0ull) break;
        __builtin_amdgcn_s_sleep(2);
      }
      __builtin_amdgcn_fence(__ATOMIC_ACQUIRE, "agent");
    }
    __syncthreads();
  }

  // ---- final FC: out[wg][0..7] = h1_final[wg] @ Wfc^T + bfc ----
  const unsigned short* hf = h1b + (size_t)(Bsz * Hh);  // buffer 1 holds h1[127]
  float* red = (float*)smem;                            // W region dead now
  const int cc = tid & 7, ksl = tid >> 3;
  const unsigned short* hr = hf + (size_t)wg * Hh + ksl * 16;
  const float* wr = Wfc + (size_t)cc * Hh + ksl * 16;
  float s = 0.f;
  #pragma unroll
  for (int k = 0; k < 16; ++k) s += bf2f(hr[k]) * wr[k];
  red[tid] = s;
  __syncthreads();
  if (tid < 8) {
    float a = bfc[tid];
    #pragma unroll
    for (int i = 0; i < 32; ++i) a += red[i * 8 + tid];
    out[wg * 8 + tid] = a;
  }
}

extern "C" void kernel_launch(void* const* d_in, const int* in_sizes, int n_in,
                              void* d_out, int out_size, void* d_ws, size_t ws_size,
                              hipStream_t stream) {
  if (ws_size < (size_t)WS_ZERO_BYTES) return;  // loud fail instead of corruption

  const float* x   = (const float*)d_in[0];
  const float* Wx0 = (const float*)d_in[1];
  const float* bx0 = (const float*)d_in[2];
  const float* Wh0 = (const float*)d_in[3];
  const float* Wc0 = (const float*)d_in[4];
  const float* Wx1 = (const float*)d_in[5];
  const float* bx1 = (const float*)d_in[6];
  const float* Wh1 = (const float*)d_in[7];
  const float* Wc1 = (const float*)d_in[8];
  const float* Wfc = (const float*)d_in[9];
  const float* bfc = (const float*)d_in[10];
  float* out = (float*)d_out;
  unsigned char* ws = (unsigned char*)d_ws;

  (void)hipMemsetAsync(d_ws, 0, WS_ZERO_BYTES, stream);
  (void)hipFuncSetAttribute(reinterpret_cast<const void*>(lstm_fused),
                            hipFuncAttributeMaxDynamicSharedMemorySize, DYN_SHMEM);
  void* args[] = {&x, &Wx0, &bx0, &Wh0, &Wc0, &Wx1, &bx1, &Wh1, &Wc1, &Wfc, &bfc, &out, &ws};
  (void)hipLaunchCooperativeKernel((void*)lstm_fused, dim3(256), dim3(256), args,
                                   (unsigned int)DYN_SHMEM, stream);
}